// Round 4
// baseline (584.415 us; speedup 1.0000x reference)
//
#include <hip/hip_runtime.h>
#include <math.h>

#define D 64            // feature dim (both layers)
#define SCAN_T 1024     // threads in the single-block scan

// ---------------- zero int buffer ----------------
__global__ void zero_int_kernel(int* p, int n) {
    int i = blockIdx.x * blockDim.x + threadIdx.x;
    if (i < n) p[i] = 0;
}

// ---------------- count in-degree (edges only) ----------------
__global__ void count_kernel(const int* __restrict__ col, int* cnt, int E) {
    int e = blockIdx.x * blockDim.x + threadIdx.x;
    if (e < E) atomicAdd(&cnt[col[e]], 1);
}

// ---------------- single-block exclusive scan + dinv ----------------
// off[i] = sum(cnt[0..i-1]);  dinv[i] = rsqrt(1 + cnt[i])  (self-loop -> deg>=1)
__global__ void scan_kernel(const int* __restrict__ cnt, int* __restrict__ off,
                            float* __restrict__ dinv, int n) {
    __shared__ int psum[SCAN_T];
    int t = threadIdx.x;
    int chunk = (n + SCAN_T - 1) / SCAN_T;
    int lo = t * chunk;
    int hi = lo + chunk; if (hi > n) hi = n;
    int s = 0;
    for (int i = lo; i < hi; ++i) s += cnt[i];
    psum[t] = s;
    __syncthreads();
    for (int ofs = 1; ofs < SCAN_T; ofs <<= 1) {
        int v = (t >= ofs) ? psum[t - ofs] : 0;
        __syncthreads();
        psum[t] += v;
        __syncthreads();
    }
    int base = (t == 0) ? 0 : psum[t - 1];
    for (int i = lo; i < hi; ++i) {
        off[i] = base;
        base += cnt[i];
        dinv[i] = rsqrtf(1.0f + (float)cnt[i]);
    }
}

// ---------------- CSR fill: adj[pos] = src node; off becomes inclusive end ----------------
__global__ void fill_kernel(const int* __restrict__ row, const int* __restrict__ col,
                            int* off, int* __restrict__ adj, int E) {
    int e = blockIdx.x * blockDim.x + threadIdx.x;
    if (e < E) {
        int pos = atomicAdd(&off[col[e]], 1);
        adj[pos] = row[e];
    }
}

// ---------------- dense GEMM: Y[n,64] = act(X[n,64]) @ W[64,64] ----------------
// W held in registers: lane = 16*kg + c4 layout... actually lane = (kg<<4)|c4:
//   c4 = lane & 15 : output column group (cols 4*c4 .. 4*c4+3)
//   kg = lane >> 4 : k-range [16*kg, 16*kg+16)
// Each lane: wreg[16] float4 = W[k][4*c4..4*c4+3] for its 16 k values.
// Per row: broadcast-load x chunks, 16 float4 FMAs, reduce across kg via shfl_xor.
__device__ __forceinline__ float4 fma4(float s, float4 w, float4 a) {
    a.x = fmaf(s, w.x, a.x); a.y = fmaf(s, w.y, a.y);
    a.z = fmaf(s, w.z, a.z); a.w = fmaf(s, w.w, a.w);
    return a;
}

__global__ void gemm64_reg_kernel(const float* __restrict__ X, const float* __restrict__ W,
                                  float* __restrict__ Y, int n, int applyRelu) {
    int gtid = blockIdx.x * blockDim.x + threadIdx.x;
    int wv = gtid >> 6;                         // global wave id
    int nw = (gridDim.x * blockDim.x) >> 6;     // total waves
    int lane = threadIdx.x & 63;
    int c4 = lane & 15;
    int kg = lane >> 4;

    float4 wreg[16];
    #pragma unroll
    for (int t = 0; t < 16; ++t)
        wreg[t] = ((const float4*)W)[(kg * 16 + t) * 16 + c4];

    for (int r = wv; r < n; r += nw) {
        const float4* xr = (const float4*)(X + (size_t)r * D) + kg * 4;
        float4 acc = make_float4(0.f, 0.f, 0.f, 0.f);
        #pragma unroll
        for (int t4 = 0; t4 < 4; ++t4) {
            float4 xv = xr[t4];                 // 16-way broadcast within kg group
            if (applyRelu) {
                xv.x = fmaxf(xv.x, 0.f); xv.y = fmaxf(xv.y, 0.f);
                xv.z = fmaxf(xv.z, 0.f); xv.w = fmaxf(xv.w, 0.f);
            }
            acc = fma4(xv.x, wreg[t4 * 4 + 0], acc);
            acc = fma4(xv.y, wreg[t4 * 4 + 1], acc);
            acc = fma4(xv.z, wreg[t4 * 4 + 2], acc);
            acc = fma4(xv.w, wreg[t4 * 4 + 3], acc);
        }
        // reduce across the 4 kg groups (lanes lane^16, lane^32)
        acc.x += __shfl_xor(acc.x, 16, 64); acc.y += __shfl_xor(acc.y, 16, 64);
        acc.z += __shfl_xor(acc.z, 16, 64); acc.w += __shfl_xor(acc.w, 16, 64);
        acc.x += __shfl_xor(acc.x, 32, 64); acc.y += __shfl_xor(acc.y, 32, 64);
        acc.z += __shfl_xor(acc.z, 32, 64); acc.w += __shfl_xor(acc.w, 32, 64);
        if (lane < 16)
            ((float4*)(Y + (size_t)r * D))[c4] = acc;
    }
}

// ---------------- pull aggregation: one wave per node, 4 neighbors in flight ----------------
// lane = (g<<4)|l : g = neighbor slot 0..3, l = float4 chunk 0..15
// h[i,:] = xw[i,:]*dinv[i]^2 + b + sum_{r in N_in(i)} xw[r,:]*dinv[r]*dinv[i]
// DOTS=0: write h row. DOTS=1: write adot[i]=relu(h)@wlin[0:64], bdot[i]=relu(h)@wlin[64:128]
template <int DOTS>
__global__ void agg_kernel(const float* __restrict__ xw, const float* __restrict__ dinv,
                           const int* __restrict__ off, const int* __restrict__ adj,
                           const float* __restrict__ b, float* __restrict__ out,
                           const float* __restrict__ wlin,
                           float* __restrict__ adot, float* __restrict__ bdot, int n) {
    int wid = blockIdx.x * 4 + (threadIdx.x >> 6);
    if (wid >= n) return;
    int lane = threadIdx.x & 63;
    int l = lane & 15;      // float4 chunk of the 64-wide row
    int g = lane >> 4;      // neighbor slot
    int start = (wid == 0) ? 0 : off[wid - 1];   // shifted-cursor: off holds inclusive ends
    int end = off[wid];
    float di = dinv[wid];

    float4 acc = make_float4(0.f, 0.f, 0.f, 0.f);
    if (g == 0) {           // self-loop + bias, added once
        float4 v = ((const float4*)xw)[(size_t)wid * 16 + l];
        float4 bb = ((const float4*)b)[l];
        float s = di * di;
        acc.x = fmaf(v.x, s, bb.x); acc.y = fmaf(v.y, s, bb.y);
        acc.z = fmaf(v.z, s, bb.z); acc.w = fmaf(v.w, s, bb.w);
    }
    for (int p = start; p < end; p += 4) {
        int idx = p + g;
        if (idx < end) {
            int r = adj[idx];
            float s = dinv[r] * di;
            float4 v = ((const float4*)xw)[(size_t)r * 16 + l];
            acc.x = fmaf(v.x, s, acc.x); acc.y = fmaf(v.y, s, acc.y);
            acc.z = fmaf(v.z, s, acc.z); acc.w = fmaf(v.w, s, acc.w);
        }
    }
    // reduce across the 4 neighbor-slot groups
    acc.x += __shfl_xor(acc.x, 16, 64); acc.y += __shfl_xor(acc.y, 16, 64);
    acc.z += __shfl_xor(acc.z, 16, 64); acc.w += __shfl_xor(acc.w, 16, 64);
    acc.x += __shfl_xor(acc.x, 32, 64); acc.y += __shfl_xor(acc.y, 32, 64);
    acc.z += __shfl_xor(acc.z, 32, 64); acc.w += __shfl_xor(acc.w, 32, 64);

    if (DOTS) {
        // all lanes hold chunk l's final h values (duplicated across g)
        float4 hv = acc;
        hv.x = fmaxf(hv.x, 0.f); hv.y = fmaxf(hv.y, 0.f);
        hv.z = fmaxf(hv.z, 0.f); hv.w = fmaxf(hv.w, 0.f);
        float4 wa = ((const float4*)wlin)[l];
        float4 wb = ((const float4*)wlin)[16 + l];
        float pa = hv.x * wa.x + hv.y * wa.y + hv.z * wa.z + hv.w * wa.w;
        float pb = hv.x * wb.x + hv.y * wb.y + hv.z * wb.z + hv.w * wb.w;
        // sum over l = 0..15 (within each 16-lane group; groups identical)
        #pragma unroll
        for (int o = 8; o > 0; o >>= 1) {
            pa += __shfl_xor(pa, o, 64);
            pb += __shfl_xor(pb, o, 64);
        }
        if (lane == 0) { adot[wid] = pa; bdot[wid] = pb; }
    } else {
        if (lane < 16)
            ((float4*)(out + (size_t)wid * D))[l] = acc;
    }
}

// ---------------- edge output: sigmoid(adot[row] + bdot[col] + blin) ----------------
__global__ void edge_out_kernel(const int* __restrict__ row, const int* __restrict__ col,
                                const float* __restrict__ adot, const float* __restrict__ bdot,
                                const float* __restrict__ blin, float* __restrict__ out, int E) {
    int e = blockIdx.x * blockDim.x + threadIdx.x;
    if (e >= E) return;
    float z = adot[row[e]] + bdot[col[e]] + blin[0];
    out[e] = 1.f / (1.f + expf(-z));
}

// ---------------- launch ----------------
extern "C" void kernel_launch(void* const* d_in, const int* in_sizes, int n_in,
                              void* d_out, int out_size, void* d_ws, size_t ws_size,
                              hipStream_t stream) {
    const float* x     = (const float*)d_in[0];
    const int*   ei    = (const int*)d_in[1];
    const float* w1    = (const float*)d_in[2];
    const float* b1    = (const float*)d_in[3];
    const float* w2    = (const float*)d_in[4];
    const float* b2    = (const float*)d_in[5];
    const float* w_lin = (const float*)d_in[6];
    const float* b_lin = (const float*)d_in[7];
    float* out = (float*)d_out;

    int n = in_sizes[0] / D;        // 100000
    int E = in_sizes[1] / 2;        // 1000000
    const int* row = ei;
    const int* col = ei + E;

    // ---- workspace bump allocator (256B aligned) ----
    char* ws = (char*)d_ws;
    size_t cur = 0;
    auto alloc = [&](size_t bytes) -> void* {
        void* p = ws + cur;
        cur += (bytes + 255) / 256 * 256;
        return p;
    };
    int*   cnt  = (int*)  alloc((size_t)n * sizeof(int));
    int*   off  = (int*)  alloc((size_t)n * sizeof(int));
    float* dinv = (float*)alloc((size_t)n * sizeof(float));
    int*   adj  = (int*)  alloc((size_t)E * sizeof(int));
    float* adot = (float*)alloc((size_t)n * sizeof(float));
    float* bdot = (float*)alloc((size_t)n * sizeof(float));
    float* bufA = (float*)alloc((size_t)n * D * sizeof(float));   // xw
    float* bufB = (float*)alloc((size_t)n * D * sizeof(float));   // h1

    const int BT = 256;
    int gN    = (n + BT - 1) / BT;
    int gE    = (E + BT - 1) / BT;
    int gWave = (n + 3) / 4;                      // 4 waves (nodes) per block
    int gGemm = 1024;                             // grid-stride: 4096 waves, ~24 rows each

    // ---- CSR build + normalization ----
    zero_int_kernel<<<gN, BT, 0, stream>>>(cnt, n);
    count_kernel<<<gE, BT, 0, stream>>>(col, cnt, E);
    scan_kernel<<<1, SCAN_T, 0, stream>>>(cnt, off, dinv, n);
    fill_kernel<<<gE, BT, 0, stream>>>(row, col, off, adj, E);
    // off[i] now = inclusive end of node i's adjacency; start = off[i-1] (0 for i=0)

    // ---- layer 1: h1 = agg(x @ w1) + b1  (relu deferred to next load) ----
    gemm64_reg_kernel<<<gGemm, BT, 0, stream>>>(x, w1, bufA, n, 0);
    agg_kernel<0><<<gWave, BT, 0, stream>>>(bufA, dinv, off, adj, b1, bufB,
                                            nullptr, nullptr, nullptr, n);

    // ---- layer 2: xw2 = relu(h1) @ w2; agg fused with edge-head node dots ----
    gemm64_reg_kernel<<<gGemm, BT, 0, stream>>>(bufB, w2, bufA, n, 1);
    agg_kernel<1><<<gWave, BT, 0, stream>>>(bufA, dinv, off, adj, b2, nullptr,
                                            w_lin, adot, bdot, n);

    // ---- edge prediction head ----
    edge_out_kernel<<<gE, BT, 0, stream>>>(row, col, adot, bdot, b_lin, out, E);
}

// Round 5
// 379.334 us; speedup vs baseline: 1.5406x; 1.5406x over previous
//
#include <hip/hip_runtime.h>
#include <math.h>

#define D 64              // feature dim (both layers)
#define SCAN_BLOCK 256
#define SCAN_ITEMS 4      // cnt elements per thread
#define SCAN_TILE (SCAN_BLOCK * SCAN_ITEMS)   // 1024 per block

// ---------------- zero int buffer ----------------
__global__ void zero_int_kernel(int* p, int n) {
    int i = blockIdx.x * blockDim.x + threadIdx.x;
    if (i < n) p[i] = 0;
}

// ---------------- count in-degree (edges only) ----------------
__global__ void count_kernel(const int* __restrict__ col, int* cnt, int E) {
    int e = blockIdx.x * blockDim.x + threadIdx.x;
    if (e < E) atomicAdd(&cnt[col[e]], 1);
}

// ---------------- 3-phase device-wide exclusive scan ----------------
// Phase A: per-block sums of cnt
__global__ void block_reduce_kernel(const int* __restrict__ cnt, int* __restrict__ blockSums, int n) {
    int b = blockIdx.x, t = threadIdx.x;
    int base = b * SCAN_TILE + t * SCAN_ITEMS;
    int s = 0;
    #pragma unroll
    for (int k = 0; k < SCAN_ITEMS; ++k) {
        int i = base + k;
        if (i < n) s += cnt[i];
    }
    #pragma unroll
    for (int o = 32; o > 0; o >>= 1) s += __shfl_xor(s, o, 64);
    __shared__ int wsum[SCAN_BLOCK / 64];
    if ((t & 63) == 0) wsum[t >> 6] = s;
    __syncthreads();
    if (t == 0) {
        int tot = 0;
        #pragma unroll
        for (int w = 0; w < SCAN_BLOCK / 64; ++w) tot += wsum[w];
        blockSums[b] = tot;
    }
}

// Phase B: exclusive scan of block sums (nb <= 256; nb = ceil(100000/1024) = 98)
__global__ void scan_sums_kernel(int* blockSums, int nb) {
    __shared__ int sh[256];
    int t = threadIdx.x;
    int v = (t < nb) ? blockSums[t] : 0;
    sh[t] = v;
    __syncthreads();
    for (int o = 1; o < 256; o <<= 1) {
        int u = (t >= o) ? sh[t - o] : 0;
        __syncthreads();
        sh[t] += u;
        __syncthreads();
    }
    if (t < nb) blockSums[t] = (t == 0) ? 0 : sh[t - 1];   // exclusive base per block
}

// Phase C: off[i] = exclusive start; dinv[i] = rsqrt(1 + cnt[i])
__global__ void scan_apply_kernel(const int* __restrict__ cnt, const int* __restrict__ blockSums,
                                  int* __restrict__ off, float* __restrict__ dinv, int n) {
    int b = blockIdx.x, t = threadIdx.x;
    int base = b * SCAN_TILE + t * SCAN_ITEMS;
    int c[SCAN_ITEMS];
    int s = 0;
    #pragma unroll
    for (int k = 0; k < SCAN_ITEMS; ++k) {
        int i = base + k;
        c[k] = (i < n) ? cnt[i] : 0;
        s += c[k];
    }
    __shared__ int sh[SCAN_BLOCK];
    sh[t] = s;
    __syncthreads();
    for (int o = 1; o < SCAN_BLOCK; o <<= 1) {
        int u = (t >= o) ? sh[t - o] : 0;
        __syncthreads();
        sh[t] += u;
        __syncthreads();
    }
    int run = blockSums[b] + ((t == 0) ? 0 : sh[t - 1]);
    #pragma unroll
    for (int k = 0; k < SCAN_ITEMS; ++k) {
        int i = base + k;
        if (i < n) {
            off[i] = run;            // exclusive start (fill converts to inclusive end)
            run += c[k];
            dinv[i] = rsqrtf(1.0f + (float)c[k]);
        }
    }
}

// ---------------- CSR fill: adj[pos] = src node; off becomes inclusive end ----------------
__global__ void fill_kernel(const int* __restrict__ row, const int* __restrict__ col,
                            int* off, int* __restrict__ adj, int E) {
    int e = blockIdx.x * blockDim.x + threadIdx.x;
    if (e < E) {
        int pos = atomicAdd(&off[col[e]], 1);
        adj[pos] = row[e];
    }
}

// ---------------- dense GEMM: Y[n,64] = act(X[n,64]) @ W[64,64] ----------------
// lane = (kg<<4)|c4: c4 = output column group (4 cols), kg = k-range [16*kg,16*kg+16)
// Each lane holds its 16-float4 slice of W in registers, amortized over grid-strided rows.
__device__ __forceinline__ float4 fma4(float s, float4 w, float4 a) {
    a.x = fmaf(s, w.x, a.x); a.y = fmaf(s, w.y, a.y);
    a.z = fmaf(s, w.z, a.z); a.w = fmaf(s, w.w, a.w);
    return a;
}

__global__ void gemm64_reg_kernel(const float* __restrict__ X, const float* __restrict__ W,
                                  float* __restrict__ Y, int n, int applyRelu) {
    int gtid = blockIdx.x * blockDim.x + threadIdx.x;
    int wv = gtid >> 6;                         // global wave id
    int nw = (gridDim.x * blockDim.x) >> 6;     // total waves
    int lane = threadIdx.x & 63;
    int c4 = lane & 15;
    int kg = lane >> 4;

    float4 wreg[16];
    #pragma unroll
    for (int t = 0; t < 16; ++t)
        wreg[t] = ((const float4*)W)[(kg * 16 + t) * 16 + c4];

    for (int r = wv; r < n; r += nw) {
        const float4* xr = (const float4*)(X + (size_t)r * D) + kg * 4;
        float4 acc = make_float4(0.f, 0.f, 0.f, 0.f);
        #pragma unroll
        for (int t4 = 0; t4 < 4; ++t4) {
            float4 xv = xr[t4];
            if (applyRelu) {
                xv.x = fmaxf(xv.x, 0.f); xv.y = fmaxf(xv.y, 0.f);
                xv.z = fmaxf(xv.z, 0.f); xv.w = fmaxf(xv.w, 0.f);
            }
            acc = fma4(xv.x, wreg[t4 * 4 + 0], acc);
            acc = fma4(xv.y, wreg[t4 * 4 + 1], acc);
            acc = fma4(xv.z, wreg[t4 * 4 + 2], acc);
            acc = fma4(xv.w, wreg[t4 * 4 + 3], acc);
        }
        acc.x += __shfl_xor(acc.x, 16, 64); acc.y += __shfl_xor(acc.y, 16, 64);
        acc.z += __shfl_xor(acc.z, 16, 64); acc.w += __shfl_xor(acc.w, 16, 64);
        acc.x += __shfl_xor(acc.x, 32, 64); acc.y += __shfl_xor(acc.y, 32, 64);
        acc.z += __shfl_xor(acc.z, 32, 64); acc.w += __shfl_xor(acc.w, 32, 64);
        if (lane < 16)
            ((float4*)(Y + (size_t)r * D))[c4] = acc;
    }
}

// ---------------- pull aggregation: one wave per node, 4 neighbors in flight ----------------
// lane = (g<<4)|l : g = neighbor slot 0..3, l = float4 chunk 0..15
// DOTS=0: write h row. DOTS=1: write adot[i]=relu(h)@wlin[0:64], bdot[i]=relu(h)@wlin[64:128]
template <int DOTS>
__global__ void agg_kernel(const float* __restrict__ xw, const float* __restrict__ dinv,
                           const int* __restrict__ off, const int* __restrict__ adj,
                           const float* __restrict__ b, float* __restrict__ out,
                           const float* __restrict__ wlin,
                           float* __restrict__ adot, float* __restrict__ bdot, int n) {
    int wid = blockIdx.x * 4 + (threadIdx.x >> 6);
    if (wid >= n) return;
    int lane = threadIdx.x & 63;
    int l = lane & 15;
    int g = lane >> 4;
    int start = (wid == 0) ? 0 : off[wid - 1];
    int end = off[wid];
    float di = dinv[wid];

    float4 acc = make_float4(0.f, 0.f, 0.f, 0.f);
    if (g == 0) {           // self-loop + bias, added once
        float4 v = ((const float4*)xw)[(size_t)wid * 16 + l];
        float4 bb = ((const float4*)b)[l];
        float s = di * di;
        acc.x = fmaf(v.x, s, bb.x); acc.y = fmaf(v.y, s, bb.y);
        acc.z = fmaf(v.z, s, bb.z); acc.w = fmaf(v.w, s, bb.w);
    }
    for (int p = start; p < end; p += 4) {
        int idx = p + g;
        if (idx < end) {
            int r = adj[idx];
            float s = dinv[r] * di;
            float4 v = ((const float4*)xw)[(size_t)r * 16 + l];
            acc.x = fmaf(v.x, s, acc.x); acc.y = fmaf(v.y, s, acc.y);
            acc.z = fmaf(v.z, s, acc.z); acc.w = fmaf(v.w, s, acc.w);
        }
    }
    acc.x += __shfl_xor(acc.x, 16, 64); acc.y += __shfl_xor(acc.y, 16, 64);
    acc.z += __shfl_xor(acc.z, 16, 64); acc.w += __shfl_xor(acc.w, 16, 64);
    acc.x += __shfl_xor(acc.x, 32, 64); acc.y += __shfl_xor(acc.y, 32, 64);
    acc.z += __shfl_xor(acc.z, 32, 64); acc.w += __shfl_xor(acc.w, 32, 64);

    if (DOTS) {
        float4 hv = acc;
        hv.x = fmaxf(hv.x, 0.f); hv.y = fmaxf(hv.y, 0.f);
        hv.z = fmaxf(hv.z, 0.f); hv.w = fmaxf(hv.w, 0.f);
        float4 wa = ((const float4*)wlin)[l];
        float4 wb = ((const float4*)wlin)[16 + l];
        float pa = hv.x * wa.x + hv.y * wa.y + hv.z * wa.z + hv.w * wa.w;
        float pb = hv.x * wb.x + hv.y * wb.y + hv.z * wb.z + hv.w * wb.w;
        #pragma unroll
        for (int o = 8; o > 0; o >>= 1) {
            pa += __shfl_xor(pa, o, 64);
            pb += __shfl_xor(pb, o, 64);
        }
        if (lane == 0) { adot[wid] = pa; bdot[wid] = pb; }
    } else {
        if (lane < 16)
            ((float4*)(out + (size_t)wid * D))[l] = acc;
    }
}

// ---------------- edge output: sigmoid(adot[row] + bdot[col] + blin) ----------------
__global__ void edge_out_kernel(const int* __restrict__ row, const int* __restrict__ col,
                                const float* __restrict__ adot, const float* __restrict__ bdot,
                                const float* __restrict__ blin, float* __restrict__ out, int E) {
    int e = blockIdx.x * blockDim.x + threadIdx.x;
    if (e >= E) return;
    float z = adot[row[e]] + bdot[col[e]] + blin[0];
    out[e] = 1.f / (1.f + expf(-z));
}

// ---------------- launch ----------------
extern "C" void kernel_launch(void* const* d_in, const int* in_sizes, int n_in,
                              void* d_out, int out_size, void* d_ws, size_t ws_size,
                              hipStream_t stream) {
    const float* x     = (const float*)d_in[0];
    const int*   ei    = (const int*)d_in[1];
    const float* w1    = (const float*)d_in[2];
    const float* b1    = (const float*)d_in[3];
    const float* w2    = (const float*)d_in[4];
    const float* b2    = (const float*)d_in[5];
    const float* w_lin = (const float*)d_in[6];
    const float* b_lin = (const float*)d_in[7];
    float* out = (float*)d_out;

    int n = in_sizes[0] / D;        // 100000
    int E = in_sizes[1] / 2;        // 1000000
    const int* row = ei;
    const int* col = ei + E;

    // ---- workspace bump allocator (256B aligned) ----
    char* ws = (char*)d_ws;
    size_t cur = 0;
    auto alloc = [&](size_t bytes) -> void* {
        void* p = ws + cur;
        cur += (bytes + 255) / 256 * 256;
        return p;
    };
    int nScanBlocks = (n + SCAN_TILE - 1) / SCAN_TILE;   // 98 for n=100000 (must be <=256)
    int*   cnt   = (int*)  alloc((size_t)n * sizeof(int));
    int*   off   = (int*)  alloc((size_t)n * sizeof(int));
    float* dinv  = (float*)alloc((size_t)n * sizeof(float));
    int*   bsums = (int*)  alloc((size_t)nScanBlocks * sizeof(int));
    int*   adj   = (int*)  alloc((size_t)E * sizeof(int));
    float* adot  = (float*)alloc((size_t)n * sizeof(float));
    float* bdot  = (float*)alloc((size_t)n * sizeof(float));
    float* bufA  = (float*)alloc((size_t)n * D * sizeof(float));   // xw
    float* bufB  = (float*)alloc((size_t)n * D * sizeof(float));   // h1

    const int BT = 256;
    int gN    = (n + BT - 1) / BT;
    int gE    = (E + BT - 1) / BT;
    int gWave = (n + 3) / 4;                      // 4 waves (nodes) per block
    int gGemm = 1024;                             // grid-stride: 4096 waves, ~24 rows each

    // ---- CSR build + normalization ----
    zero_int_kernel<<<gN, BT, 0, stream>>>(cnt, n);
    count_kernel<<<gE, BT, 0, stream>>>(col, cnt, E);
    block_reduce_kernel<<<nScanBlocks, SCAN_BLOCK, 0, stream>>>(cnt, bsums, n);
    scan_sums_kernel<<<1, 256, 0, stream>>>(bsums, nScanBlocks);
    scan_apply_kernel<<<nScanBlocks, SCAN_BLOCK, 0, stream>>>(cnt, bsums, off, dinv, n);
    fill_kernel<<<gE, BT, 0, stream>>>(row, col, off, adj, E);
    // off[i] now = inclusive end of node i's adjacency; start = off[i-1] (0 for i=0)

    // ---- layer 1: h1 = agg(x @ w1) + b1  (relu deferred to next load) ----
    gemm64_reg_kernel<<<gGemm, BT, 0, stream>>>(x, w1, bufA, n, 0);
    agg_kernel<0><<<gWave, BT, 0, stream>>>(bufA, dinv, off, adj, b1, bufB,
                                            nullptr, nullptr, nullptr, n);

    // ---- layer 2: xw2 = relu(h1) @ w2; agg fused with edge-head node dots ----
    gemm64_reg_kernel<<<gGemm, BT, 0, stream>>>(bufB, w2, bufA, n, 1);
    agg_kernel<1><<<gWave, BT, 0, stream>>>(bufA, dinv, off, adj, b2, nullptr,
                                            w_lin, adot, bdot, n);

    // ---- edge prediction head ----
    edge_out_kernel<<<gE, BT, 0, stream>>>(row, col, adot, bdot, b_lin, out, E);
}

// Round 8
// 361.853 us; speedup vs baseline: 1.6151x; 1.0483x over previous
//
#include <hip/hip_runtime.h>
#include <math.h>

#define D 64              // feature dim (both layers)
#define SCAN_BLOCK 256
#define SCAN_ITEMS 4      // cnt elements per thread
#define SCAN_TILE (SCAN_BLOCK * SCAN_ITEMS)   // 1024 per block
#define NREG 8            // XCD-aligned regions for atomic-heavy kernels
#define FILL_CHUNK 4096   // edges per chunk in regionized kernels

// ---------------- zero int buffer ----------------
__global__ void zero_int_kernel(int* p, int n) {
    int i = blockIdx.x * blockDim.x + threadIdx.x;
    if (i < n) p[i] = 0;
}

// ---------------- regionized in-degree count ----------------
// block (c, r=blockIdx&7): scan edge chunk c, count only cols in [r*n/8,(r+1)*n/8).
// Each cnt line is then written by one XCD's L2 only (round-robin block->XCD
// heuristic; correctness is placement-independent).
__global__ void count_region_kernel(const int* __restrict__ col, int* cnt, int E, int n) {
    int r = blockIdx.x & (NREG - 1);
    int c = blockIdx.x >> 3;
    int lo = (int)(((long long)r * n) / NREG);
    int hi = (int)(((long long)(r + 1) * n) / NREG);
    int e0 = c * FILL_CHUNK;
    int e1 = min(E, e0 + FILL_CHUNK);
    for (int e = e0 + (int)threadIdx.x; e < e1; e += (int)blockDim.x) {
        int cl = col[e];
        if (cl >= lo && cl < hi) atomicAdd(&cnt[cl], 1);
    }
}

// ---------------- 3-phase device-wide exclusive scan ----------------
__global__ void block_reduce_kernel(const int* __restrict__ cnt, int* __restrict__ blockSums, int n) {
    int b = blockIdx.x, t = threadIdx.x;
    int base = b * SCAN_TILE + t * SCAN_ITEMS;
    int s = 0;
    #pragma unroll
    for (int k = 0; k < SCAN_ITEMS; ++k) {
        int i = base + k;
        if (i < n) s += cnt[i];
    }
    #pragma unroll
    for (int o = 32; o > 0; o >>= 1) s += __shfl_xor(s, o, 64);
    __shared__ int wsum[SCAN_BLOCK / 64];
    if ((t & 63) == 0) wsum[t >> 6] = s;
    __syncthreads();
    if (t == 0) {
        int tot = 0;
        #pragma unroll
        for (int w = 0; w < SCAN_BLOCK / 64; ++w) tot += wsum[w];
        blockSums[b] = tot;
    }
}

__global__ void scan_sums_kernel(int* blockSums, int nb) {
    __shared__ int sh[256];
    int t = threadIdx.x;
    int v = (t < nb) ? blockSums[t] : 0;
    sh[t] = v;
    __syncthreads();
    for (int o = 1; o < 256; o <<= 1) {
        int u = (t >= o) ? sh[t - o] : 0;
        __syncthreads();
        sh[t] += u;
        __syncthreads();
    }
    if (t < nb) blockSums[t] = (t == 0) ? 0 : sh[t - 1];   // exclusive base per block
}

__global__ void scan_apply_kernel(const int* __restrict__ cnt, const int* __restrict__ blockSums,
                                  int* __restrict__ off, float* __restrict__ dinv, int n) {
    int b = blockIdx.x, t = threadIdx.x;
    int base = b * SCAN_TILE + t * SCAN_ITEMS;
    int c[SCAN_ITEMS];
    int s = 0;
    #pragma unroll
    for (int k = 0; k < SCAN_ITEMS; ++k) {
        int i = base + k;
        c[k] = (i < n) ? cnt[i] : 0;
        s += c[k];
    }
    __shared__ int sh[SCAN_BLOCK];
    sh[t] = s;
    __syncthreads();
    for (int o = 1; o < SCAN_BLOCK; o <<= 1) {
        int u = (t >= o) ? sh[t - o] : 0;
        __syncthreads();
        sh[t] += u;
        __syncthreads();
    }
    int run = blockSums[b] + ((t == 0) ? 0 : sh[t - 1]);
    #pragma unroll
    for (int k = 0; k < SCAN_ITEMS; ++k) {
        int i = base + k;
        if (i < n) {
            off[i] = run;            // exclusive start (fill converts to inclusive end)
            run += c[k];
            dinv[i] = rsqrtf(1.0f + (float)c[k]);
        }
    }
}

// ---------------- region boundaries: split CSR position space into 8 equal chunks ----------------
// colBound[k] = smallest col with off[col] >= k*E/8  (off = exclusive starts, monotone)
__global__ void region_bounds_kernel(const int* __restrict__ off, int* __restrict__ colBound,
                                     int n, int E) {
    int k = threadIdx.x;
    if (k > NREG) return;
    if (k == 0) { colBound[0] = 0; return; }
    if (k == NREG) { colBound[NREG] = n; return; }
    long long target = ((long long)k * E) / NREG;
    int lo = 0, hi = n;
    while (lo < hi) {
        int mid = (lo + hi) >> 1;
        if ((long long)off[mid] < target) lo = mid + 1; else hi = mid;
    }
    colBound[k] = lo;
}

// ---------------- regionized CSR fill ----------------
__global__ void fill_region_kernel(const int* __restrict__ row, const int* __restrict__ col,
                                   const int* __restrict__ colBound,
                                   int* off, int* __restrict__ adj, int E) {
    int r = blockIdx.x & (NREG - 1);
    int c = blockIdx.x >> 3;
    int lo = colBound[r], hi = colBound[r + 1];
    int e0 = c * FILL_CHUNK;
    int e1 = min(E, e0 + FILL_CHUNK);
    for (int e = e0 + (int)threadIdx.x; e < e1; e += (int)blockDim.x) {
        int cl = col[e];
        if (cl >= lo && cl < hi) {
            int pos = atomicAdd(&off[cl], 1);
            adj[pos] = row[e];
        }
    }
}

// ---------------- dense GEMM: Y[n,64] = act(X[n,64]) @ W[64,64] ----------------
__device__ __forceinline__ float4 fma4(float s, float4 w, float4 a) {
    a.x = fmaf(s, w.x, a.x); a.y = fmaf(s, w.y, a.y);
    a.z = fmaf(s, w.z, a.z); a.w = fmaf(s, w.w, a.w);
    return a;
}

__global__ void gemm64_reg_kernel(const float* __restrict__ X, const float* __restrict__ W,
                                  float* __restrict__ Y, int n, int applyRelu) {
    int gtid = blockIdx.x * blockDim.x + threadIdx.x;
    int wv = gtid >> 6;                         // global wave id
    int nw = (gridDim.x * blockDim.x) >> 6;     // total waves
    int lane = threadIdx.x & 63;
    int c4 = lane & 15;
    int kg = lane >> 4;

    float4 wreg[16];
    #pragma unroll
    for (int t = 0; t < 16; ++t)
        wreg[t] = ((const float4*)W)[(kg * 16 + t) * 16 + c4];

    for (int r = wv; r < n; r += nw) {
        const float4* xr = (const float4*)(X + (size_t)r * D) + kg * 4;
        float4 acc = make_float4(0.f, 0.f, 0.f, 0.f);
        #pragma unroll
        for (int t4 = 0; t4 < 4; ++t4) {
            float4 xv = xr[t4];
            if (applyRelu) {
                xv.x = fmaxf(xv.x, 0.f); xv.y = fmaxf(xv.y, 0.f);
                xv.z = fmaxf(xv.z, 0.f); xv.w = fmaxf(xv.w, 0.f);
            }
            acc = fma4(xv.x, wreg[t4 * 4 + 0], acc);
            acc = fma4(xv.y, wreg[t4 * 4 + 1], acc);
            acc = fma4(xv.z, wreg[t4 * 4 + 2], acc);
            acc = fma4(xv.w, wreg[t4 * 4 + 3], acc);
        }
        acc.x += __shfl_xor(acc.x, 16, 64); acc.y += __shfl_xor(acc.y, 16, 64);
        acc.z += __shfl_xor(acc.z, 16, 64); acc.w += __shfl_xor(acc.w, 16, 64);
        acc.x += __shfl_xor(acc.x, 32, 64); acc.y += __shfl_xor(acc.y, 32, 64);
        acc.z += __shfl_xor(acc.z, 32, 64); acc.w += __shfl_xor(acc.w, 32, 64);
        if (lane < 16)
            ((float4*)(Y + (size_t)r * D))[c4] = acc;
    }
}

// ---------------- pull aggregation: one wave per node, 4 neighbors in flight ----------------
template <int DOTS>
__global__ void agg_kernel(const float* __restrict__ xw, const float* __restrict__ dinv,
                           const int* __restrict__ off, const int* __restrict__ adj,
                           const float* __restrict__ b, float* __restrict__ out,
                           const float* __restrict__ wlin,
                           float* __restrict__ adot, float* __restrict__ bdot, int n) {
    int wid = blockIdx.x * 4 + (threadIdx.x >> 6);
    if (wid >= n) return;
    int lane = threadIdx.x & 63;
    int l = lane & 15;
    int g = lane >> 4;
    int start = (wid == 0) ? 0 : off[wid - 1];
    int end = off[wid];
    float di = dinv[wid];

    float4 acc = make_float4(0.f, 0.f, 0.f, 0.f);
    if (g == 0) {           // self-loop + bias, added once
        float4 v = ((const float4*)xw)[(size_t)wid * 16 + l];
        float4 bb = ((const float4*)b)[l];
        float s = di * di;
        acc.x = fmaf(v.x, s, bb.x); acc.y = fmaf(v.y, s, bb.y);
        acc.z = fmaf(v.z, s, bb.z); acc.w = fmaf(v.w, s, bb.w);
    }
    for (int p = start; p < end; p += 4) {
        int idx = p + g;
        if (idx < end) {
            int r = adj[idx];
            float s = dinv[r] * di;
            float4 v = ((const float4*)xw)[(size_t)r * 16 + l];
            acc.x = fmaf(v.x, s, acc.x); acc.y = fmaf(v.y, s, acc.y);
            acc.z = fmaf(v.z, s, acc.z); acc.w = fmaf(v.w, s, acc.w);
        }
    }
    acc.x += __shfl_xor(acc.x, 16, 64); acc.y += __shfl_xor(acc.y, 16, 64);
    acc.z += __shfl_xor(acc.z, 16, 64); acc.w += __shfl_xor(acc.w, 16, 64);
    acc.x += __shfl_xor(acc.x, 32, 64); acc.y += __shfl_xor(acc.y, 32, 64);
    acc.z += __shfl_xor(acc.z, 32, 64); acc.w += __shfl_xor(acc.w, 32, 64);

    if (DOTS) {
        float4 hv = acc;
        hv.x = fmaxf(hv.x, 0.f); hv.y = fmaxf(hv.y, 0.f);
        hv.z = fmaxf(hv.z, 0.f); hv.w = fmaxf(hv.w, 0.f);
        float4 wa = ((const float4*)wlin)[l];
        float4 wb = ((const float4*)wlin)[16 + l];
        float pa = hv.x * wa.x + hv.y * wa.y + hv.z * wa.z + hv.w * wa.w;
        float pb = hv.x * wb.x + hv.y * wb.y + hv.z * wb.z + hv.w * wb.w;
        #pragma unroll
        for (int o = 8; o > 0; o >>= 1) {
            pa += __shfl_xor(pa, o, 64);
            pb += __shfl_xor(pb, o, 64);
        }
        if (lane == 0) { adot[wid] = pa; bdot[wid] = pb; }
    } else {
        if (lane < 16)
            ((float4*)(out + (size_t)wid * D))[l] = acc;
    }
}

// ---------------- edge output: sigmoid(adot[row] + bdot[col] + blin) ----------------
__global__ void edge_out_kernel(const int* __restrict__ row, const int* __restrict__ col,
                                const float* __restrict__ adot, const float* __restrict__ bdot,
                                const float* __restrict__ blin, float* __restrict__ out, int E) {
    int e = blockIdx.x * blockDim.x + threadIdx.x;
    if (e >= E) return;
    float z = adot[row[e]] + bdot[col[e]] + blin[0];
    out[e] = 1.f / (1.f + expf(-z));
}

// ---------------- launch ----------------
extern "C" void kernel_launch(void* const* d_in, const int* in_sizes, int n_in,
                              void* d_out, int out_size, void* d_ws, size_t ws_size,
                              hipStream_t stream) {
    const float* x     = (const float*)d_in[0];
    const int*   ei    = (const int*)d_in[1];
    const float* w1    = (const float*)d_in[2];
    const float* b1    = (const float*)d_in[3];
    const float* w2    = (const float*)d_in[4];
    const float* b2    = (const float*)d_in[5];
    const float* w_lin = (const float*)d_in[6];
    const float* b_lin = (const float*)d_in[7];
    float* out = (float*)d_out;

    int n = in_sizes[0] / D;        // 100000
    int E = in_sizes[1] / 2;        // 1000000
    const int* row = ei;
    const int* col = ei + E;

    // ---- workspace bump allocator (256B aligned) ----
    char* ws = (char*)d_ws;
    size_t cur = 0;
    auto alloc = [&](size_t bytes) -> void* {
        void* p = ws + cur;
        cur += (bytes + 255) / 256 * 256;
        return p;
    };
    int nScanBlocks = (n + SCAN_TILE - 1) / SCAN_TILE;   // 98 for n=100000 (<=256)
    int*   cnt    = (int*)  alloc((size_t)n * sizeof(int));
    int*   off    = (int*)  alloc((size_t)n * sizeof(int));
    float* dinv   = (float*)alloc((size_t)n * sizeof(float));
    int*   bsums  = (int*)  alloc((size_t)nScanBlocks * sizeof(int));
    int*   cbound = (int*)  alloc((size_t)(NREG + 1) * sizeof(int));
    int*   adj    = (int*)  alloc((size_t)E * sizeof(int));
    float* adot   = (float*)alloc((size_t)n * sizeof(float));
    float* bdot   = (float*)alloc((size_t)n * sizeof(float));
    float* bufA   = (float*)alloc((size_t)n * D * sizeof(float));   // xw
    float* bufB   = (float*)alloc((size_t)n * D * sizeof(float));   // h1

    const int BT = 256;
    int gN     = (n + BT - 1) / BT;
    int gE     = (E + BT - 1) / BT;
    int gWave  = (n + 3) / 4;                     // 4 waves (nodes) per block
    int gGemm  = 1024;                            // grid-stride GEMM
    int nChunk = (E + FILL_CHUNK - 1) / FILL_CHUNK;
    int gReg   = nChunk * NREG;

    // ---- CSR build + normalization ----
    zero_int_kernel<<<gN, BT, 0, stream>>>(cnt, n);
    count_region_kernel<<<gReg, BT, 0, stream>>>(col, cnt, E, n);
    block_reduce_kernel<<<nScanBlocks, SCAN_BLOCK, 0, stream>>>(cnt, bsums, n);
    scan_sums_kernel<<<1, 256, 0, stream>>>(bsums, nScanBlocks);
    scan_apply_kernel<<<nScanBlocks, SCAN_BLOCK, 0, stream>>>(cnt, bsums, off, dinv, n);
    region_bounds_kernel<<<1, 64, 0, stream>>>(off, cbound, n, E);
    fill_region_kernel<<<gReg, BT, 0, stream>>>(row, col, cbound, off, adj, E);
    // off[i] now = inclusive end of node i's adjacency; start = off[i-1] (0 for i=0)

    // ---- layer 1: h1 = agg(x @ w1) + b1  (relu deferred to next load) ----
    gemm64_reg_kernel<<<gGemm, BT, 0, stream>>>(x, w1, bufA, n, 0);
    agg_kernel<0><<<gWave, BT, 0, stream>>>(bufA, dinv, off, adj, b1, bufB,
                                            nullptr, nullptr, nullptr, n);

    // ---- layer 2: xw2 = relu(h1) @ w2; agg fused with edge-head node dots ----
    gemm64_reg_kernel<<<gGemm, BT, 0, stream>>>(bufB, w2, bufA, n, 1);
    agg_kernel<1><<<gWave, BT, 0, stream>>>(bufA, dinv, off, adj, b2, nullptr,
                                            w_lin, adot, bdot, n);

    // ---- edge prediction head ----
    edge_out_kernel<<<gE, BT, 0, stream>>>(row, col, adot, bdot, b_lin, out, E);
}

// Round 10
// 350.346 us; speedup vs baseline: 1.6681x; 1.0328x over previous
//
#include <hip/hip_runtime.h>
#include <math.h>

#define D 64              // feature dim (both layers)
#define SCAN_BLOCK 256
#define SCAN_ITEMS 4      // cnt elements per thread
#define SCAN_TILE (SCAN_BLOCK * SCAN_ITEMS)   // 1024 per block
#define NREG 8            // XCD-aligned regions for atomic-heavy kernels
#define FILL_CHUNK 4096   // edges per chunk in regionized kernels

// ---------------- zero int buffer ----------------
__global__ void zero_int_kernel(int* p, int n) {
    int i = blockIdx.x * blockDim.x + threadIdx.x;
    if (i < n) p[i] = 0;
}

// ---------------- regionized in-degree count ----------------
__global__ void count_region_kernel(const int* __restrict__ col, int* cnt, int E, int n) {
    int r = blockIdx.x & (NREG - 1);
    int c = blockIdx.x >> 3;
    int lo = (int)(((long long)r * n) / NREG);
    int hi = (int)(((long long)(r + 1) * n) / NREG);
    int e0 = c * FILL_CHUNK;
    int e1 = min(E, e0 + FILL_CHUNK);
    for (int e = e0 + (int)threadIdx.x; e < e1; e += (int)blockDim.x) {
        int cl = col[e];
        if (cl >= lo && cl < hi) atomicAdd(&cnt[cl], 1);
    }
}

// ---------------- 3-phase device-wide exclusive scan ----------------
__global__ void block_reduce_kernel(const int* __restrict__ cnt, int* __restrict__ blockSums, int n) {
    int b = blockIdx.x, t = threadIdx.x;
    int base = b * SCAN_TILE + t * SCAN_ITEMS;
    int s = 0;
    #pragma unroll
    for (int k = 0; k < SCAN_ITEMS; ++k) {
        int i = base + k;
        if (i < n) s += cnt[i];
    }
    #pragma unroll
    for (int o = 32; o > 0; o >>= 1) s += __shfl_xor(s, o, 64);
    __shared__ int wsum[SCAN_BLOCK / 64];
    if ((t & 63) == 0) wsum[t >> 6] = s;
    __syncthreads();
    if (t == 0) {
        int tot = 0;
        #pragma unroll
        for (int w = 0; w < SCAN_BLOCK / 64; ++w) tot += wsum[w];
        blockSums[b] = tot;
    }
}

__global__ void scan_sums_kernel(int* blockSums, int nb) {
    __shared__ int sh[256];
    int t = threadIdx.x;
    int v = (t < nb) ? blockSums[t] : 0;
    sh[t] = v;
    __syncthreads();
    for (int o = 1; o < 256; o <<= 1) {
        int u = (t >= o) ? sh[t - o] : 0;
        __syncthreads();
        sh[t] += u;
        __syncthreads();
    }
    if (t < nb) blockSums[t] = (t == 0) ? 0 : sh[t - 1];   // exclusive base per block
}

__global__ void scan_apply_kernel(const int* __restrict__ cnt, const int* __restrict__ blockSums,
                                  int* __restrict__ off, float* __restrict__ dinv, int n) {
    int b = blockIdx.x, t = threadIdx.x;
    int base = b * SCAN_TILE + t * SCAN_ITEMS;
    int c[SCAN_ITEMS];
    int s = 0;
    #pragma unroll
    for (int k = 0; k < SCAN_ITEMS; ++k) {
        int i = base + k;
        c[k] = (i < n) ? cnt[i] : 0;
        s += c[k];
    }
    __shared__ int sh[SCAN_BLOCK];
    sh[t] = s;
    __syncthreads();
    for (int o = 1; o < SCAN_BLOCK; o <<= 1) {
        int u = (t >= o) ? sh[t - o] : 0;
        __syncthreads();
        sh[t] += u;
        __syncthreads();
    }
    int run = blockSums[b] + ((t == 0) ? 0 : sh[t - 1]);
    #pragma unroll
    for (int k = 0; k < SCAN_ITEMS; ++k) {
        int i = base + k;
        if (i < n) {
            off[i] = run;            // exclusive start (fill converts to inclusive end)
            run += c[k];
            dinv[i] = rsqrtf(1.0f + (float)c[k]);
        }
    }
}

// ---------------- region boundaries ----------------
__global__ void region_bounds_kernel(const int* __restrict__ off, int* __restrict__ colBound,
                                     int n, int E) {
    int k = threadIdx.x;
    if (k > NREG) return;
    if (k == 0) { colBound[0] = 0; return; }
    if (k == NREG) { colBound[NREG] = n; return; }
    long long target = ((long long)k * E) / NREG;
    int lo = 0, hi = n;
    while (lo < hi) {
        int mid = (lo + hi) >> 1;
        if ((long long)off[mid] < target) lo = mid + 1; else hi = mid;
    }
    colBound[k] = lo;
}

// ---------------- regionized CSR fill ----------------
__global__ void fill_region_kernel(const int* __restrict__ row, const int* __restrict__ col,
                                   const int* __restrict__ colBound,
                                   int* off, int* __restrict__ adj, int E) {
    int r = blockIdx.x & (NREG - 1);
    int c = blockIdx.x >> 3;
    int lo = colBound[r], hi = colBound[r + 1];
    int e0 = c * FILL_CHUNK;
    int e1 = min(E, e0 + FILL_CHUNK);
    for (int e = e0 + (int)threadIdx.x; e < e1; e += (int)blockDim.x) {
        int cl = col[e];
        if (cl >= lo && cl < hi) {
            int pos = atomicAdd(&off[cl], 1);
            adj[pos] = row[e];
        }
    }
}

// ---------------- dense GEMM: Y[n,64] = act(X[n,64]) @ W[64,64] ----------------
__device__ __forceinline__ float4 fma4(float s, float4 w, float4 a) {
    a.x = fmaf(s, w.x, a.x); a.y = fmaf(s, w.y, a.y);
    a.z = fmaf(s, w.z, a.z); a.w = fmaf(s, w.w, a.w);
    return a;
}

__global__ void gemm64_reg_kernel(const float* __restrict__ X, const float* __restrict__ W,
                                  float* __restrict__ Y, int n, int applyRelu) {
    int gtid = blockIdx.x * blockDim.x + threadIdx.x;
    int wv = gtid >> 6;                         // global wave id
    int nw = (gridDim.x * blockDim.x) >> 6;     // total waves
    int lane = threadIdx.x & 63;
    int c4 = lane & 15;
    int kg = lane >> 4;

    float4 wreg[16];
    #pragma unroll
    for (int t = 0; t < 16; ++t)
        wreg[t] = ((const float4*)W)[(kg * 16 + t) * 16 + c4];

    for (int r = wv; r < n; r += nw) {
        const float4* xr = (const float4*)(X + (size_t)r * D) + kg * 4;
        float4 acc = make_float4(0.f, 0.f, 0.f, 0.f);
        #pragma unroll
        for (int t4 = 0; t4 < 4; ++t4) {
            float4 xv = xr[t4];
            if (applyRelu) {
                xv.x = fmaxf(xv.x, 0.f); xv.y = fmaxf(xv.y, 0.f);
                xv.z = fmaxf(xv.z, 0.f); xv.w = fmaxf(xv.w, 0.f);
            }
            acc = fma4(xv.x, wreg[t4 * 4 + 0], acc);
            acc = fma4(xv.y, wreg[t4 * 4 + 1], acc);
            acc = fma4(xv.z, wreg[t4 * 4 + 2], acc);
            acc = fma4(xv.w, wreg[t4 * 4 + 3], acc);
        }
        acc.x += __shfl_xor(acc.x, 16, 64); acc.y += __shfl_xor(acc.y, 16, 64);
        acc.z += __shfl_xor(acc.z, 16, 64); acc.w += __shfl_xor(acc.w, 16, 64);
        acc.x += __shfl_xor(acc.x, 32, 64); acc.y += __shfl_xor(acc.y, 32, 64);
        acc.z += __shfl_xor(acc.z, 32, 64); acc.w += __shfl_xor(acc.w, 32, 64);
        if (lane < 16)
            ((float4*)(Y + (size_t)r * D))[c4] = acc;
    }
}

// ---------------- pull aggregation: one wave per node ----------------
// Phase 1 per 64-neighbor chunk: all lanes cooperatively load adj (coalesced)
// and s = dinv[adj]*di; invalid slots (k >= deg) get s = 0.
// Phase 2: WAVE-UNIFORM loop (kk < mm, mm = m rounded up to 8; trip count
// mm/8 for every lane -> no divergence around __shfl). Each group g issues
// two independent row gathers (kk, kk+4) then applies them sequentially into
// ONE accumulator -> summation order is bit-identical to the round-8 kernel
// (g, g+4, g+8, ... ascending); padded slots contribute exact +0.
template <int DOTS>
__global__ void agg_kernel(const float* __restrict__ xw, const float* __restrict__ dinv,
                           const int* __restrict__ off, const int* __restrict__ adj,
                           const float* __restrict__ b, float* __restrict__ out,
                           const float* __restrict__ wlin,
                           float* __restrict__ adot, float* __restrict__ bdot, int n) {
    int wid = blockIdx.x * 4 + (threadIdx.x >> 6);
    if (wid >= n) return;
    int lane = threadIdx.x & 63;
    int l = lane & 15;      // float4 chunk of the row
    int g = lane >> 4;      // neighbor slot group 0..3
    int start = (wid == 0) ? 0 : off[wid - 1];
    int end = off[wid];
    int deg = end - start;
    float di = dinv[wid];

    float4 acc = make_float4(0.f, 0.f, 0.f, 0.f);
    if (g == 0) {           // self-loop + bias, added once
        float4 v = ((const float4*)xw)[(size_t)wid * 16 + l];
        float4 bb = ((const float4*)b)[l];
        float s = di * di;
        acc.x = fmaf(v.x, s, bb.x); acc.y = fmaf(v.y, s, bb.y);
        acc.z = fmaf(v.z, s, bb.z); acc.w = fmaf(v.w, s, bb.w);
    }

    for (int base = 0; base < deg; base += 64) {
        // phase 1: cooperative index+scale prefetch (uniform flow before shfl)
        int k = base + lane;
        int a = 0; float s = 0.f;
        if (k < deg) {
            a = adj[start + k];          // coalesced 256B wave load
            s = dinv[a] * di;            // one 4B gather per lane
        }
        int m = min(64, deg - base);
        int mm = (m + 7) & ~7;           // wave-uniform padded bound
        // phase 2: uniform trip count mm/8 for every lane
        for (int kk = g; kk < mm; kk += 8) {
            int r0 = __shfl(a, kk, 64);
            int r1 = __shfl(a, kk + 4, 64);
            float s0 = __shfl(s, kk, 64);
            float s1 = __shfl(s, kk + 4, 64);
            float4 v0 = ((const float4*)xw)[(size_t)r0 * 16 + l];   // independent
            float4 v1 = ((const float4*)xw)[(size_t)r1 * 16 + l];   // gathers
            acc.x = fmaf(v0.x, s0, acc.x); acc.y = fmaf(v0.y, s0, acc.y);
            acc.z = fmaf(v0.z, s0, acc.z); acc.w = fmaf(v0.w, s0, acc.w);
            acc.x = fmaf(v1.x, s1, acc.x); acc.y = fmaf(v1.y, s1, acc.y);
            acc.z = fmaf(v1.z, s1, acc.z); acc.w = fmaf(v1.w, s1, acc.w);
        }
    }
    // reduce across the 4 neighbor-slot groups
    acc.x += __shfl_xor(acc.x, 16, 64); acc.y += __shfl_xor(acc.y, 16, 64);
    acc.z += __shfl_xor(acc.z, 16, 64); acc.w += __shfl_xor(acc.w, 16, 64);
    acc.x += __shfl_xor(acc.x, 32, 64); acc.y += __shfl_xor(acc.y, 32, 64);
    acc.z += __shfl_xor(acc.z, 32, 64); acc.w += __shfl_xor(acc.w, 32, 64);

    if (DOTS) {
        float4 hv = acc;
        hv.x = fmaxf(hv.x, 0.f); hv.y = fmaxf(hv.y, 0.f);
        hv.z = fmaxf(hv.z, 0.f); hv.w = fmaxf(hv.w, 0.f);
        float4 wa = ((const float4*)wlin)[l];
        float4 wb = ((const float4*)wlin)[16 + l];
        float pa = hv.x * wa.x + hv.y * wa.y + hv.z * wa.z + hv.w * wa.w;
        float pb = hv.x * wb.x + hv.y * wb.y + hv.z * wb.z + hv.w * wb.w;
        #pragma unroll
        for (int o = 8; o > 0; o >>= 1) {
            pa += __shfl_xor(pa, o, 64);
            pb += __shfl_xor(pb, o, 64);
        }
        if (lane == 0) { adot[wid] = pa; bdot[wid] = pb; }
    } else {
        if (lane < 16)
            ((float4*)(out + (size_t)wid * D))[l] = acc;
    }
}

// ---------------- edge output: sigmoid(adot[row] + bdot[col] + blin) ----------------
__global__ void edge_out_kernel(const int* __restrict__ row, const int* __restrict__ col,
                                const float* __restrict__ adot, const float* __restrict__ bdot,
                                const float* __restrict__ blin, float* __restrict__ out, int E) {
    int e = blockIdx.x * blockDim.x + threadIdx.x;
    if (e >= E) return;
    float z = adot[row[e]] + bdot[col[e]] + blin[0];
    out[e] = 1.f / (1.f + expf(-z));
}

// ---------------- launch ----------------
extern "C" void kernel_launch(void* const* d_in, const int* in_sizes, int n_in,
                              void* d_out, int out_size, void* d_ws, size_t ws_size,
                              hipStream_t stream) {
    const float* x     = (const float*)d_in[0];
    const int*   ei    = (const int*)d_in[1];
    const float* w1    = (const float*)d_in[2];
    const float* b1    = (const float*)d_in[3];
    const float* w2    = (const float*)d_in[4];
    const float* b2    = (const float*)d_in[5];
    const float* w_lin = (const float*)d_in[6];
    const float* b_lin = (const float*)d_in[7];
    float* out = (float*)d_out;

    int n = in_sizes[0] / D;        // 100000
    int E = in_sizes[1] / 2;        // 1000000
    const int* row = ei;
    const int* col = ei + E;

    // ---- workspace bump allocator (256B aligned) ----
    char* ws = (char*)d_ws;
    size_t cur = 0;
    auto alloc = [&](size_t bytes) -> void* {
        void* p = ws + cur;
        cur += (bytes + 255) / 256 * 256;
        return p;
    };
    int nScanBlocks = (n + SCAN_TILE - 1) / SCAN_TILE;   // 98 for n=100000 (<=256)
    int*   cnt    = (int*)  alloc((size_t)n * sizeof(int));
    int*   off    = (int*)  alloc((size_t)n * sizeof(int));
    float* dinv   = (float*)alloc((size_t)n * sizeof(float));
    int*   bsums  = (int*)  alloc((size_t)nScanBlocks * sizeof(int));
    int*   cbound = (int*)  alloc((size_t)(NREG + 1) * sizeof(int));
    int*   adj    = (int*)  alloc((size_t)E * sizeof(int));
    float* adot   = (float*)alloc((size_t)n * sizeof(float));
    float* bdot   = (float*)alloc((size_t)n * sizeof(float));
    float* bufA   = (float*)alloc((size_t)n * D * sizeof(float));   // xw
    float* bufB   = (float*)alloc((size_t)n * D * sizeof(float));   // h1

    const int BT = 256;
    int gN     = (n + BT - 1) / BT;
    int gE     = (E + BT - 1) / BT;
    int gWave  = (n + 3) / 4;                     // 4 waves (nodes) per block
    int gGemm  = 1024;                            // grid-stride GEMM
    int nChunk = (E + FILL_CHUNK - 1) / FILL_CHUNK;
    int gReg   = nChunk * NREG;

    // ---- CSR build + normalization ----
    zero_int_kernel<<<gN, BT, 0, stream>>>(cnt, n);
    count_region_kernel<<<gReg, BT, 0, stream>>>(col, cnt, E, n);
    block_reduce_kernel<<<nScanBlocks, SCAN_BLOCK, 0, stream>>>(cnt, bsums, n);
    scan_sums_kernel<<<1, 256, 0, stream>>>(bsums, nScanBlocks);
    scan_apply_kernel<<<nScanBlocks, SCAN_BLOCK, 0, stream>>>(cnt, bsums, off, dinv, n);
    region_bounds_kernel<<<1, 64, 0, stream>>>(off, cbound, n, E);
    fill_region_kernel<<<gReg, BT, 0, stream>>>(row, col, cbound, off, adj, E);
    // off[i] now = inclusive end of node i's adjacency; start = off[i-1] (0 for i=0)

    // ---- layer 1: h1 = agg(x @ w1) + b1  (relu deferred to next load) ----
    gemm64_reg_kernel<<<gGemm, BT, 0, stream>>>(x, w1, bufA, n, 0);
    agg_kernel<0><<<gWave, BT, 0, stream>>>(bufA, dinv, off, adj, b1, bufB,
                                            nullptr, nullptr, nullptr, n);

    // ---- layer 2: xw2 = relu(h1) @ w2; agg fused with edge-head node dots ----
    gemm64_reg_kernel<<<gGemm, BT, 0, stream>>>(bufB, w2, bufA, n, 1);
    agg_kernel<1><<<gWave, BT, 0, stream>>>(bufA, dinv, off, adj, b2, nullptr,
                                            w_lin, adot, bdot, n);

    // ---- edge prediction head ----
    edge_out_kernel<<<gE, BT, 0, stream>>>(row, col, adot, bdot, b_lin, out, E);
}

// Round 11
// 337.918 us; speedup vs baseline: 1.7295x; 1.0368x over previous
//
#include <hip/hip_runtime.h>
#include <math.h>

#define D 64              // feature dim (both layers)
#define SCAN_BLOCK 256
#define SCAN_ITEMS 4      // cnt elements per thread
#define SCAN_TILE (SCAN_BLOCK * SCAN_ITEMS)   // 1024 per block
#define NREG 8            // XCD-aligned regions for atomic-heavy kernels
#define FILL_CHUNK 4096   // edges per chunk in regionized kernels

// bf16 helpers (manual, RTNE encode / shift decode)
__device__ __forceinline__ unsigned short f2bf(float f) {
    union { float f; unsigned int i; } v; v.f = f;
    unsigned int u = v.i;
    unsigned int r = (u + 0x7FFFu + ((u >> 16) & 1u)) >> 16;   // round-to-nearest-even
    return (unsigned short)r;
}
__device__ __forceinline__ float bf2f(unsigned short u) {
    union { unsigned int i; float f; } v; v.i = ((unsigned int)u) << 16;
    return v.f;
}

// ---------------- zero int buffer ----------------
__global__ void zero_int_kernel(int* p, int n) {
    int i = blockIdx.x * blockDim.x + threadIdx.x;
    if (i < n) p[i] = 0;
}

// ---------------- regionized in-degree count ----------------
__global__ void count_region_kernel(const int* __restrict__ col, int* cnt, int E, int n) {
    int r = blockIdx.x & (NREG - 1);
    int c = blockIdx.x >> 3;
    int lo = (int)(((long long)r * n) / NREG);
    int hi = (int)(((long long)(r + 1) * n) / NREG);
    int e0 = c * FILL_CHUNK;
    int e1 = min(E, e0 + FILL_CHUNK);
    for (int e = e0 + (int)threadIdx.x; e < e1; e += (int)blockDim.x) {
        int cl = col[e];
        if (cl >= lo && cl < hi) atomicAdd(&cnt[cl], 1);
    }
}

// ---------------- 3-phase device-wide exclusive scan ----------------
__global__ void block_reduce_kernel(const int* __restrict__ cnt, int* __restrict__ blockSums, int n) {
    int b = blockIdx.x, t = threadIdx.x;
    int base = b * SCAN_TILE + t * SCAN_ITEMS;
    int s = 0;
    #pragma unroll
    for (int k = 0; k < SCAN_ITEMS; ++k) {
        int i = base + k;
        if (i < n) s += cnt[i];
    }
    #pragma unroll
    for (int o = 32; o > 0; o >>= 1) s += __shfl_xor(s, o, 64);
    __shared__ int wsum[SCAN_BLOCK / 64];
    if ((t & 63) == 0) wsum[t >> 6] = s;
    __syncthreads();
    if (t == 0) {
        int tot = 0;
        #pragma unroll
        for (int w = 0; w < SCAN_BLOCK / 64; ++w) tot += wsum[w];
        blockSums[b] = tot;
    }
}

__global__ void scan_sums_kernel(int* blockSums, int nb) {
    __shared__ int sh[256];
    int t = threadIdx.x;
    int v = (t < nb) ? blockSums[t] : 0;
    sh[t] = v;
    __syncthreads();
    for (int o = 1; o < 256; o <<= 1) {
        int u = (t >= o) ? sh[t - o] : 0;
        __syncthreads();
        sh[t] += u;
        __syncthreads();
    }
    if (t < nb) blockSums[t] = (t == 0) ? 0 : sh[t - 1];   // exclusive base per block
}

__global__ void scan_apply_kernel(const int* __restrict__ cnt, const int* __restrict__ blockSums,
                                  int* __restrict__ off, float* __restrict__ dinv, int n) {
    int b = blockIdx.x, t = threadIdx.x;
    int base = b * SCAN_TILE + t * SCAN_ITEMS;
    int c[SCAN_ITEMS];
    int s = 0;
    #pragma unroll
    for (int k = 0; k < SCAN_ITEMS; ++k) {
        int i = base + k;
        c[k] = (i < n) ? cnt[i] : 0;
        s += c[k];
    }
    __shared__ int sh[SCAN_BLOCK];
    sh[t] = s;
    __syncthreads();
    for (int o = 1; o < SCAN_BLOCK; o <<= 1) {
        int u = (t >= o) ? sh[t - o] : 0;
        __syncthreads();
        sh[t] += u;
        __syncthreads();
    }
    int run = blockSums[b] + ((t == 0) ? 0 : sh[t - 1]);
    #pragma unroll
    for (int k = 0; k < SCAN_ITEMS; ++k) {
        int i = base + k;
        if (i < n) {
            off[i] = run;            // exclusive start (fill converts to inclusive end)
            run += c[k];
            dinv[i] = rsqrtf(1.0f + (float)c[k]);
        }
    }
}

// ---------------- region boundaries ----------------
__global__ void region_bounds_kernel(const int* __restrict__ off, int* __restrict__ colBound,
                                     int n, int E) {
    int k = threadIdx.x;
    if (k > NREG) return;
    if (k == 0) { colBound[0] = 0; return; }
    if (k == NREG) { colBound[NREG] = n; return; }
    long long target = ((long long)k * E) / NREG;
    int lo = 0, hi = n;
    while (lo < hi) {
        int mid = (lo + hi) >> 1;
        if ((long long)off[mid] < target) lo = mid + 1; else hi = mid;
    }
    colBound[k] = lo;
}

// ---------------- regionized CSR fill ----------------
__global__ void fill_region_kernel(const int* __restrict__ row, const int* __restrict__ col,
                                   const int* __restrict__ colBound,
                                   int* off, int* __restrict__ adj, int E) {
    int r = blockIdx.x & (NREG - 1);
    int c = blockIdx.x >> 3;
    int lo = colBound[r], hi = colBound[r + 1];
    int e0 = c * FILL_CHUNK;
    int e1 = min(E, e0 + FILL_CHUNK);
    for (int e = e0 + (int)threadIdx.x; e < e1; e += (int)blockDim.x) {
        int cl = col[e];
        if (cl >= lo && cl < hi) {
            int pos = atomicAdd(&off[cl], 1);
            adj[pos] = row[e];
        }
    }
}

// ---------------- dense GEMM: Ybf16[n,64] = act(X[n,64]) @ W[64,64] ----------------
// W in registers; output rounded RTNE to bf16 (gathered operand of agg).
__device__ __forceinline__ float4 fma4(float s, float4 w, float4 a) {
    a.x = fmaf(s, w.x, a.x); a.y = fmaf(s, w.y, a.y);
    a.z = fmaf(s, w.z, a.z); a.w = fmaf(s, w.w, a.w);
    return a;
}

__global__ void gemm64_reg_kernel(const float* __restrict__ X, const float* __restrict__ W,
                                  unsigned short* __restrict__ Y, int n, int applyRelu) {
    int gtid = blockIdx.x * blockDim.x + threadIdx.x;
    int wv = gtid >> 6;                         // global wave id
    int nw = (gridDim.x * blockDim.x) >> 6;     // total waves
    int lane = threadIdx.x & 63;
    int c4 = lane & 15;
    int kg = lane >> 4;

    float4 wreg[16];
    #pragma unroll
    for (int t = 0; t < 16; ++t)
        wreg[t] = ((const float4*)W)[(kg * 16 + t) * 16 + c4];

    for (int r = wv; r < n; r += nw) {
        const float4* xr = (const float4*)(X + (size_t)r * D) + kg * 4;
        float4 acc = make_float4(0.f, 0.f, 0.f, 0.f);
        #pragma unroll
        for (int t4 = 0; t4 < 4; ++t4) {
            float4 xv = xr[t4];
            if (applyRelu) {
                xv.x = fmaxf(xv.x, 0.f); xv.y = fmaxf(xv.y, 0.f);
                xv.z = fmaxf(xv.z, 0.f); xv.w = fmaxf(xv.w, 0.f);
            }
            acc = fma4(xv.x, wreg[t4 * 4 + 0], acc);
            acc = fma4(xv.y, wreg[t4 * 4 + 1], acc);
            acc = fma4(xv.z, wreg[t4 * 4 + 2], acc);
            acc = fma4(xv.w, wreg[t4 * 4 + 3], acc);
        }
        acc.x += __shfl_xor(acc.x, 16, 64); acc.y += __shfl_xor(acc.y, 16, 64);
        acc.z += __shfl_xor(acc.z, 16, 64); acc.w += __shfl_xor(acc.w, 16, 64);
        acc.x += __shfl_xor(acc.x, 32, 64); acc.y += __shfl_xor(acc.y, 32, 64);
        acc.z += __shfl_xor(acc.z, 32, 64); acc.w += __shfl_xor(acc.w, 32, 64);
        if (lane < 16) {
            ushort4 o;
            o.x = f2bf(acc.x); o.y = f2bf(acc.y);
            o.z = f2bf(acc.z); o.w = f2bf(acc.w);
            ((ushort4*)(Y + (size_t)r * D))[c4] = o;   // 8B per lane, 128B per row
        }
    }
}

// ---------------- pull aggregation: one wave per node, bf16 gather payload ----------------
// Identical structure/order to the f32 version; each lane gathers ushort4 (8B,
// 4 dims) instead of float4 (16B); rows are 128B. f32 accumulate.
template <int DOTS>
__global__ void agg_kernel(const unsigned short* __restrict__ xw, const float* __restrict__ dinv,
                           const int* __restrict__ off, const int* __restrict__ adj,
                           const float* __restrict__ b, float* __restrict__ out,
                           const float* __restrict__ wlin,
                           float* __restrict__ adot, float* __restrict__ bdot, int n) {
    int wid = blockIdx.x * 4 + (threadIdx.x >> 6);
    if (wid >= n) return;
    int lane = threadIdx.x & 63;
    int l = lane & 15;      // 4-dim chunk of the row
    int g = lane >> 4;      // neighbor slot group 0..3
    int start = (wid == 0) ? 0 : off[wid - 1];
    int end = off[wid];
    int deg = end - start;
    float di = dinv[wid];
    const ushort4* xwb = (const ushort4*)xw;   // row stride = 16 ushort4

    float4 acc = make_float4(0.f, 0.f, 0.f, 0.f);
    if (g == 0) {           // self-loop + bias, added once
        ushort4 u = xwb[(size_t)wid * 16 + l];
        float4 bb = ((const float4*)b)[l];
        float s = di * di;
        acc.x = fmaf(bf2f(u.x), s, bb.x); acc.y = fmaf(bf2f(u.y), s, bb.y);
        acc.z = fmaf(bf2f(u.z), s, bb.z); acc.w = fmaf(bf2f(u.w), s, bb.w);
    }

    for (int base = 0; base < deg; base += 64) {
        // phase 1: cooperative index+scale prefetch (uniform flow before shfl)
        int k = base + lane;
        int a = 0; float s = 0.f;
        if (k < deg) {
            a = adj[start + k];          // coalesced 256B wave load
            s = dinv[a] * di;            // one 4B gather per lane
        }
        int m = min(64, deg - base);
        int mm = (m + 7) & ~7;           // wave-uniform padded bound
        // phase 2: uniform trip count; two independent 128B row gathers per iter
        for (int kk = g; kk < mm; kk += 8) {
            int r0 = __shfl(a, kk, 64);
            int r1 = __shfl(a, kk + 4, 64);
            float s0 = __shfl(s, kk, 64);
            float s1 = __shfl(s, kk + 4, 64);
            ushort4 u0 = xwb[(size_t)r0 * 16 + l];
            ushort4 u1 = xwb[(size_t)r1 * 16 + l];
            acc.x = fmaf(bf2f(u0.x), s0, acc.x); acc.y = fmaf(bf2f(u0.y), s0, acc.y);
            acc.z = fmaf(bf2f(u0.z), s0, acc.z); acc.w = fmaf(bf2f(u0.w), s0, acc.w);
            acc.x = fmaf(bf2f(u1.x), s1, acc.x); acc.y = fmaf(bf2f(u1.y), s1, acc.y);
            acc.z = fmaf(bf2f(u1.z), s1, acc.z); acc.w = fmaf(bf2f(u1.w), s1, acc.w);
        }
    }
    // reduce across the 4 neighbor-slot groups
    acc.x += __shfl_xor(acc.x, 16, 64); acc.y += __shfl_xor(acc.y, 16, 64);
    acc.z += __shfl_xor(acc.z, 16, 64); acc.w += __shfl_xor(acc.w, 16, 64);
    acc.x += __shfl_xor(acc.x, 32, 64); acc.y += __shfl_xor(acc.y, 32, 64);
    acc.z += __shfl_xor(acc.z, 32, 64); acc.w += __shfl_xor(acc.w, 32, 64);

    if (DOTS) {
        float4 hv = acc;
        hv.x = fmaxf(hv.x, 0.f); hv.y = fmaxf(hv.y, 0.f);
        hv.z = fmaxf(hv.z, 0.f); hv.w = fmaxf(hv.w, 0.f);
        float4 wa = ((const float4*)wlin)[l];
        float4 wb = ((const float4*)wlin)[16 + l];
        float pa = hv.x * wa.x + hv.y * wa.y + hv.z * wa.z + hv.w * wa.w;
        float pb = hv.x * wb.x + hv.y * wb.y + hv.z * wb.z + hv.w * wb.w;
        #pragma unroll
        for (int o = 8; o > 0; o >>= 1) {
            pa += __shfl_xor(pa, o, 64);
            pb += __shfl_xor(pb, o, 64);
        }
        if (lane == 0) { adot[wid] = pa; bdot[wid] = pb; }
    } else {
        if (lane < 16)
            ((float4*)(out + (size_t)wid * D))[l] = acc;
    }
}

// ---------------- edge output: sigmoid(adot[row] + bdot[col] + blin) ----------------
__global__ void edge_out_kernel(const int* __restrict__ row, const int* __restrict__ col,
                                const float* __restrict__ adot, const float* __restrict__ bdot,
                                const float* __restrict__ blin, float* __restrict__ out, int E) {
    int e = blockIdx.x * blockDim.x + threadIdx.x;
    if (e >= E) return;
    float z = adot[row[e]] + bdot[col[e]] + blin[0];
    out[e] = 1.f / (1.f + expf(-z));
}

// ---------------- launch ----------------
extern "C" void kernel_launch(void* const* d_in, const int* in_sizes, int n_in,
                              void* d_out, int out_size, void* d_ws, size_t ws_size,
                              hipStream_t stream) {
    const float* x     = (const float*)d_in[0];
    const int*   ei    = (const int*)d_in[1];
    const float* w1    = (const float*)d_in[2];
    const float* b1    = (const float*)d_in[3];
    const float* w2    = (const float*)d_in[4];
    const float* b2    = (const float*)d_in[5];
    const float* w_lin = (const float*)d_in[6];
    const float* b_lin = (const float*)d_in[7];
    float* out = (float*)d_out;

    int n = in_sizes[0] / D;        // 100000
    int E = in_sizes[1] / 2;        // 1000000
    const int* row = ei;
    const int* col = ei + E;

    // ---- workspace bump allocator (256B aligned) ----
    char* ws = (char*)d_ws;
    size_t cur = 0;
    auto alloc = [&](size_t bytes) -> void* {
        void* p = ws + cur;
        cur += (bytes + 255) / 256 * 256;
        return p;
    };
    int nScanBlocks = (n + SCAN_TILE - 1) / SCAN_TILE;   // 98 for n=100000 (<=256)
    int*            cnt    = (int*)   alloc((size_t)n * sizeof(int));
    int*            off    = (int*)   alloc((size_t)n * sizeof(int));
    float*          dinv   = (float*) alloc((size_t)n * sizeof(float));
    int*            bsums  = (int*)   alloc((size_t)nScanBlocks * sizeof(int));
    int*            cbound = (int*)   alloc((size_t)(NREG + 1) * sizeof(int));
    int*            adj    = (int*)   alloc((size_t)E * sizeof(int));
    float*          adot   = (float*) alloc((size_t)n * sizeof(float));
    float*          bdot   = (float*) alloc((size_t)n * sizeof(float));
    unsigned short* bufA   = (unsigned short*)alloc((size_t)n * D * sizeof(unsigned short)); // xw bf16
    float*          bufB   = (float*) alloc((size_t)n * D * sizeof(float));                  // h1 f32

    const int BT = 256;
    int gN     = (n + BT - 1) / BT;
    int gE     = (E + BT - 1) / BT;
    int gWave  = (n + 3) / 4;                     // 4 waves (nodes) per block
    int gGemm  = 1024;                            // grid-stride GEMM
    int nChunk = (E + FILL_CHUNK - 1) / FILL_CHUNK;
    int gReg   = nChunk * NREG;

    // ---- CSR build + normalization ----
    zero_int_kernel<<<gN, BT, 0, stream>>>(cnt, n);
    count_region_kernel<<<gReg, BT, 0, stream>>>(col, cnt, E, n);
    block_reduce_kernel<<<nScanBlocks, SCAN_BLOCK, 0, stream>>>(cnt, bsums, n);
    scan_sums_kernel<<<1, 256, 0, stream>>>(bsums, nScanBlocks);
    scan_apply_kernel<<<nScanBlocks, SCAN_BLOCK, 0, stream>>>(cnt, bsums, off, dinv, n);
    region_bounds_kernel<<<1, 64, 0, stream>>>(off, cbound, n, E);
    fill_region_kernel<<<gReg, BT, 0, stream>>>(row, col, cbound, off, adj, E);
    // off[i] now = inclusive end of node i's adjacency; start = off[i-1] (0 for i=0)

    // ---- layer 1: h1 = agg(x @ w1) + b1  (relu deferred to next load) ----
    gemm64_reg_kernel<<<gGemm, BT, 0, stream>>>(x, w1, bufA, n, 0);
    agg_kernel<0><<<gWave, BT, 0, stream>>>(bufA, dinv, off, adj, b1, bufB,
                                            nullptr, nullptr, nullptr, n);

    // ---- layer 2: xw2 = relu(h1) @ w2; agg fused with edge-head node dots ----
    gemm64_reg_kernel<<<gGemm, BT, 0, stream>>>(bufB, w2, bufA, n, 1);
    agg_kernel<1><<<gWave, BT, 0, stream>>>(bufA, dinv, off, adj, b2, nullptr,
                                            w_lin, adot, bdot, n);

    // ---- edge prediction head ----
    edge_out_kernel<<<gE, BT, 0, stream>>>(row, col, adot, bdot, b_lin, out, E);
}